// Round 4
// baseline (787.714 us; speedup 1.0000x reference)
//
#include <hip/hip_runtime.h>
#include <hip/hip_bf16.h>
#include <math.h>

// Problem constants
#define BB 4
#define SS 4096
#define DM 1024
#define HH 16
#define HD 64
#define NTOK (BB * SS)          // 16384 rows
#define TSZ ((size_t)NTOK * DM) // 16777216 elements per activation plane

typedef _Float16 half8 __attribute__((ext_vector_type(8)));
typedef _Float16 half4v __attribute__((ext_vector_type(4)));
typedef float floatx4 __attribute__((ext_vector_type(4)));

__device__ __forceinline__ void gload16(const void* g, void* l) {
  __builtin_amdgcn_global_load_lds(
      (const __attribute__((address_space(1))) void*)g,
      (__attribute__((address_space(3))) void*)l, 16, 0, 0);
}

#define WAIT0 asm volatile("s_waitcnt vmcnt(0)" ::: "memory")
#define BARR __builtin_amdgcn_s_barrier()

#define MM3(A_, ah_, al_, bh_, bl_)                                   \
  A_ = __builtin_amdgcn_mfma_f32_16x16x32_f16(ah_, bh_, A_, 0, 0, 0); \
  A_ = __builtin_amdgcn_mfma_f32_16x16x32_f16(ah_, bl_, A_, 0, 0, 0); \
  A_ = __builtin_amdgcn_mfma_f32_16x16x32_f16(al_, bh_, A_, 0, 0, 0)

__device__ __forceinline__ void cvhl(const float4 u0, const float4 u1,
                                     half8& h, half8& l) {
  const float a[8] = {u0.x, u0.y, u0.z, u0.w, u1.x, u1.y, u1.z, u1.w};
#pragma unroll
  for (int e = 0; e < 8; ++e) {
    const _Float16 hh = (_Float16)a[e];
    h[e] = hh;
    l[e] = (_Float16)(a[e] - (float)hh);
  }
}

// ---------------------------------------------------------------------------
// All 4 weight matrices split into (hi,lo) f16 planes in one dispatch.
// Arena: hi/lo each 4*(1<<20) f16. Order: 0=k_w 1=v_w 2=q_w 3=o_w.
// ---------------------------------------------------------------------------
__global__ __launch_bounds__(256) void split_w4(
    const float* __restrict__ w0, const float* __restrict__ w1,
    const float* __restrict__ w2, const float* __restrict__ w3,
    _Float16* __restrict__ hi, _Float16* __restrict__ lo) {
  const int wi = blockIdx.y;
  const float* src = (wi == 0) ? w0 : (wi == 1) ? w1 : (wi == 2) ? w2 : w3;
  const int i = blockIdx.x * 256 + threadIdx.x;          // < 262144
  const size_t off = ((size_t)wi << 20) >> 2;            // in float4 units
  const float4 x = ((const float4*)src)[i];
  half4v h, l;
  h.x = (_Float16)x.x; l.x = (_Float16)(x.x - (float)h.x);
  h.y = (_Float16)x.y; l.y = (_Float16)(x.y - (float)h.y);
  h.z = (_Float16)x.z; l.z = (_Float16)(x.z - (float)h.z);
  h.w = (_Float16)x.w; l.w = (_Float16)(x.w - (float)h.w);
  ((half4v*)hi)[off + i] = h;
  ((half4v*)lo)[off + i] = l;
}

// ---------------------------------------------------------------------------
// 256x256-tile QKV GEMM, 16x16x32 f16 MFMA, SINGLE barrier per K-tile.
// All 8 staging ops for tile tt+1 issued at top of tile tt; one vmcnt(0) at
// top of tile tt+1 (full-iteration issue-to-wait gap => free). B fragments
// read once per K-tile, held in regs for both QM halves. Raw fp32 A staged
// direct via global_load_lds, hi/lo split at fragment read. XOR-swizzled
// LDS, setprio around MFMA clusters, bijective XCD swizzle.
// ---------------------------------------------------------------------------
__global__ __launch_bounds__(512, 2) void qkv_gemm9(
    const float* __restrict__ Ak, const float* __restrict__ Av,
    const float* __restrict__ Aq, const _Float16* __restrict__ WhiA,
    const _Float16* __restrict__ WloA, const float* __restrict__ bk,
    const float* __restrict__ bv, const float* __restrict__ bq,
    float* __restrict__ Ck, float* __restrict__ Cv, float* __restrict__ Cq) {
  __shared__ float sA[2][256 * 32];      // raw fp32 A tile, 32 KB per buf
  __shared__ _Float16 sB[2][256 * 64];   // f16 hi|lo pair rows, 32 KB per buf

  const int z = blockIdx.z;
  const float* A = (z == 0) ? Ak : (z == 1) ? Av : Aq;
  const float* bias = (z == 0) ? bk : (z == 1) ? bv : bq;
  float* C = (z == 0) ? Ck : (z == 1) ? Cv : Cq;
  const _Float16* Whi = WhiA + ((size_t)z << 20);
  const _Float16* Wlo = WloA + ((size_t)z << 20);

  const int t = threadIdx.x;
  const int wav = t >> 6, lane = t & 63;
  const int wr = wav >> 2, wc = wav & 3;  // 2 x 4 wave grid

  // bijective XCD swizzle: each XCD owns one (N-half, M-sixteenth) chunk
  const int wg = blockIdx.y * 4 + blockIdx.x;  // 0..255
  const int xcd = wg & 7, cidx = wg >> 3;      // cidx 0..31
  const int bm = ((xcd >> 1) * 16 + (cidx >> 1)) * 256;
  const int bn = ((xcd & 1) * 2 + (cidx & 1)) * 256;

  // --- staging source prep (source pre-swizzled so linear LDS = swizzled) ---
  const int lrow = wav * 8 + (lane >> 3);       // row within a 64-row issue
  const int cpr = (lane & 7) ^ (lane >> 3);     // global slot for dest slot l&7
  const float* pA0 = A + (size_t)(bm + lrow) * DM + cpr * 4;
  const _Float16* pB0 =
      ((cpr < 4) ? Whi : Wlo) + (size_t)(bn + lrow) * DM + (cpr & 3) * 8;
  const int ldsArow = wav * 8 * 32;  // float units (wave-uniform)
  const int ldsBrow = wav * 8 * 64;  // f16 units  (wave-uniform)

#define STA(buf, rb, k0) \
  gload16(pA0 + (size_t)(rb) * DM + (k0), &sA[buf][(rb) * 32 + ldsArow])
#define STB(buf, rb, k0) \
  gload16(pB0 + (size_t)(rb) * DM + (k0), &sB[buf][(rb) * 64 + ldsBrow])

#define STAGE_ALL(buf, k0)                          \
  STA(buf, 0, k0); STA(buf, 64, k0);                \
  STA(buf, 128, k0); STA(buf, 192, k0);             \
  STB(buf, 0, k0); STB(buf, 64, k0);                \
  STB(buf, 128, k0); STB(buf, 192, k0)

  // prologue: stage tile 0
  STAGE_ALL(0, 0);

  // --- ds_read fragment offsets (swizzled: slot ^= row&7, row&7 == fm&7) ---
  const int fm = lane & 15;
  const int sw = fm & 7;
  const int kq = lane >> 4;
  int baseA[4], baseB[2];
#pragma unroll
  for (int i = 0; i < 4; ++i) baseA[i] = (wr * 64 + i * 16 + fm) * 32;
#pragma unroll
  for (int j = 0; j < 2; ++j) baseB[j] = (wc * 32 + j * 16 + fm) * 64;
  const int aS0 = ((kq * 2) ^ sw) * 4;       // fp32 slots (16B each)
  const int aS1 = ((kq * 2 + 1) ^ sw) * 4;
  const int bSh = (kq ^ sw) * 8;             // f16 hi slot
  const int bSl = ((kq + 4) ^ sw) * 8;       // f16 lo slot

  floatx4 acc[2][4][2][2];
#pragma unroll
  for (int i = 0; i < 2; ++i)
#pragma unroll
    for (int j = 0; j < 4; ++j)
#pragma unroll
      for (int k = 0; k < 2; ++k)
#pragma unroll
        for (int l = 0; l < 2; ++l)
          acc[i][j][k][l] = (floatx4){0.f, 0.f, 0.f, 0.f};

  half8 ah[4], al[4];
  half8 b0h0, b0l0, b0h1, b0l1;   // B fragments, QN=0
  half8 b1h0, b1l0, b1h1, b1l1;   // B fragments, QN=1

#define READA_Q(cur_, QM)                                       \
  _Pragma("unroll") for (int i_ = 0; i_ < 4; ++i_) {            \
    const float4 u0_ =                                          \
        *(const float4*)&sA[cur_][baseA[i_] + (QM) * 4096 + aS0]; \
    const float4 u1_ =                                          \
        *(const float4*)&sA[cur_][baseA[i_] + (QM) * 4096 + aS1]; \
    cvhl(u0_, u1_, ah[i_], al[i_]);                             \
  }

#define RB_Q(cur_, QN, H0, L0, H1, L1)                          \
  H0 = *(const half8*)&sB[cur_][baseB[0] + (QN) * 8192 + bSh];  \
  L0 = *(const half8*)&sB[cur_][baseB[0] + (QN) * 8192 + bSl];  \
  H1 = *(const half8*)&sB[cur_][baseB[1] + (QN) * 8192 + bSh];  \
  L1 = *(const half8*)&sB[cur_][baseB[1] + (QN) * 8192 + bSl]

// one QM half: 48 MFMAs against all four B fragment pairs
#define MFMACL(QM)                                              \
  __builtin_amdgcn_s_setprio(1);                                \
  _Pragma("unroll") for (int i_ = 0; i_ < 4; ++i_) {            \
    MM3(acc[QM][i_][0][0], ah[i_], al[i_], b0h0, b0l0);         \
    MM3(acc[QM][i_][0][1], ah[i_], al[i_], b0h1, b0l1);         \
    MM3(acc[QM][i_][1][0], ah[i_], al[i_], b1h0, b1l0);         \
    MM3(acc[QM][i_][1][1], ah[i_], al[i_], b1h1, b1l1);         \
  }                                                             \
  __builtin_amdgcn_s_setprio(0)

  // main loop: tiles 0..30, single barrier per K-tile, whole-tile prefetch
  for (int tt = 0; tt < 31; ++tt) {
    const int cur = tt & 1, nxt = cur ^ 1;
    const int k1 = (tt + 1) * 32;
    WAIT0;                // drains tile tt's 8 staging ops (issued 1 iter ago)
    BARR;                 // all waves' staging landed; prev reads of nxt done
    STAGE_ALL(nxt, k1);   // issue tile tt+1 staging; waited at next iter top
    READA_Q(cur, 0);
    RB_Q(cur, 0, b0h0, b0l0, b0h1, b0l1);
    RB_Q(cur, 1, b1h0, b1l0, b1h1, b1l1);
    MFMACL(0);
    READA_Q(cur, 1);
    MFMACL(1);
  }
  // epilogue tile 31 (cur = 1), no prefetch
  WAIT0; BARR;
  READA_Q(1, 0);
  RB_Q(1, 0, b0h0, b0l0, b0h1, b0l1);
  RB_Q(1, 1, b1h0, b1l0, b1h1, b1l1);
  MFMACL(0);
  READA_Q(1, 1);
  MFMACL(1);

  const int cr = (lane >> 4) * 4;
#pragma unroll
  for (int qm = 0; qm < 2; ++qm)
#pragma unroll
    for (int i = 0; i < 4; ++i) {
      const int grow = bm + qm * 128 + wr * 64 + i * 16 + cr;
#pragma unroll
      for (int qn = 0; qn < 2; ++qn)
#pragma unroll
        for (int j = 0; j < 2; ++j) {
          const int gcol = bn + qn * 128 + wc * 32 + j * 16 + fm;
          const float bo = bias[gcol];
#pragma unroll
          for (int r = 0; r < 4; ++r)
            C[(size_t)(grow + r) * DM + gcol] = acc[qm][i][qn][j][r] + bo;
        }
    }
#undef STA
#undef STB
#undef STAGE_ALL
#undef READA_Q
#undef RB_Q
#undef MFMACL
}

// ---------------------------------------------------------------------------
// Output-projection GEMM: pure f16, A pre-split (by attn_apply_conv) into
// hi/lo planes. Same single-barrier whole-tile-prefetch schedule.
// ---------------------------------------------------------------------------
__global__ __launch_bounds__(512, 2) void o_gemm9(
    const _Float16* __restrict__ Ahi, const _Float16* __restrict__ Alo,
    const _Float16* __restrict__ Whi, const _Float16* __restrict__ Wlo,
    const float* __restrict__ bias, float* __restrict__ C) {
  __shared__ _Float16 sA[2][256 * 64];
  __shared__ _Float16 sB[2][256 * 64];

  const int t = threadIdx.x;
  const int wav = t >> 6, lane = t & 63;
  const int wr = wav >> 2, wc = wav & 3;

  const int wg = blockIdx.y * 4 + blockIdx.x;
  const int xcd = wg & 7, cidx = wg >> 3;
  const int bm = ((xcd >> 1) * 16 + (cidx >> 1)) * 256;
  const int bn = ((xcd & 1) * 2 + (cidx & 1)) * 256;

  const int lrow = wav * 8 + (lane >> 3);
  const int cpr = (lane & 7) ^ (lane >> 3);
  const _Float16* pA0 =
      ((cpr < 4) ? Ahi : Alo) + (size_t)(bm + lrow) * DM + (cpr & 3) * 8;
  const _Float16* pB0 =
      ((cpr < 4) ? Whi : Wlo) + (size_t)(bn + lrow) * DM + (cpr & 3) * 8;
  const int ldsRow = wav * 8 * 64;

#define STAO(buf, rb, k0) \
  gload16(pA0 + (size_t)(rb) * DM + (k0), &sA[buf][(rb) * 64 + ldsRow])
#define STBO(buf, rb, k0) \
  gload16(pB0 + (size_t)(rb) * DM + (k0), &sB[buf][(rb) * 64 + ldsRow])

#define STAGE_ALLO(buf, k0)                         \
  STAO(buf, 0, k0); STAO(buf, 64, k0);              \
  STAO(buf, 128, k0); STAO(buf, 192, k0);           \
  STBO(buf, 0, k0); STBO(buf, 64, k0);              \
  STBO(buf, 128, k0); STBO(buf, 192, k0)

  STAGE_ALLO(0, 0);

  const int fm = lane & 15;
  const int sw = fm & 7;
  const int kq = lane >> 4;
  int baseA[4], baseB[2];
#pragma unroll
  for (int i = 0; i < 4; ++i) baseA[i] = (wr * 64 + i * 16 + fm) * 64;
#pragma unroll
  for (int j = 0; j < 2; ++j) baseB[j] = (wc * 32 + j * 16 + fm) * 64;
  const int bSh = (kq ^ sw) * 8;
  const int bSl = ((kq + 4) ^ sw) * 8;

  floatx4 acc[2][4][2][2];
#pragma unroll
  for (int i = 0; i < 2; ++i)
#pragma unroll
    for (int j = 0; j < 4; ++j)
#pragma unroll
      for (int k = 0; k < 2; ++k)
#pragma unroll
        for (int l = 0; l < 2; ++l)
          acc[i][j][k][l] = (floatx4){0.f, 0.f, 0.f, 0.f};

  half8 ah[4], al[4];
  half8 b0h0, b0l0, b0h1, b0l1;
  half8 b1h0, b1l0, b1h1, b1l1;

#define READA_O(cur_, QM)                                                 \
  _Pragma("unroll") for (int i_ = 0; i_ < 4; ++i_) {                      \
    ah[i_] = *(const half8*)&sA[cur_][baseA[i_] + (QM) * 8192 + bSh];     \
    al[i_] = *(const half8*)&sA[cur_][baseA[i_] + (QM) * 8192 + bSl];     \
  }

#define RB_O(cur_, QN, H0, L0, H1, L1)                          \
  H0 = *(const half8*)&sB[cur_][baseB[0] + (QN) * 8192 + bSh];  \
  L0 = *(const half8*)&sB[cur_][baseB[0] + (QN) * 8192 + bSl];  \
  H1 = *(const half8*)&sB[cur_][baseB[1] + (QN) * 8192 + bSh];  \
  L1 = *(const half8*)&sB[cur_][baseB[1] + (QN) * 8192 + bSl]

#define MFMACLO(QM)                                             \
  __builtin_amdgcn_s_setprio(1);                                \
  _Pragma("unroll") for (int i_ = 0; i_ < 4; ++i_) {            \
    MM3(acc[QM][i_][0][0], ah[i_], al[i_], b0h0, b0l0);         \
    MM3(acc[QM][i_][0][1], ah[i_], al[i_], b0h1, b0l1);         \
    MM3(acc[QM][i_][1][0], ah[i_], al[i_], b1h0, b1l0);         \
    MM3(acc[QM][i_][1][1], ah[i_], al[i_], b1h1, b1l1);         \
  }                                                             \
  __builtin_amdgcn_s_setprio(0)

  for (int tt = 0; tt < 31; ++tt) {
    const int cur = tt & 1, nxt = cur ^ 1;
    const int k1 = (tt + 1) * 32;
    WAIT0;
    BARR;
    STAGE_ALLO(nxt, k1);
    READA_O(cur, 0);
    RB_O(cur, 0, b0h0, b0l0, b0h1, b0l1);
    RB_O(cur, 1, b1h0, b1l0, b1h1, b1l1);
    MFMACLO(0);
    READA_O(cur, 1);
    MFMACLO(1);
  }
  WAIT0; BARR;
  READA_O(1, 0);
  RB_O(1, 0, b0h0, b0l0, b0h1, b0l1);
  RB_O(1, 1, b1h0, b1l0, b1h1, b1l1);
  MFMACLO(0);
  READA_O(1, 1);
  MFMACLO(1);

  const int cr = (lane >> 4) * 4;
#pragma unroll
  for (int qm = 0; qm < 2; ++qm)
#pragma unroll
    for (int i = 0; i < 4; ++i) {
      const int grow = bm + qm * 128 + wr * 64 + i * 16 + cr;
#pragma unroll
      for (int qn = 0; qn < 2; ++qn)
#pragma unroll
        for (int j = 0; j < 2; ++j) {
          const int gcol = bn + qn * 128 + wc * 32 + j * 16 + fm;
          const float bo = bias[gcol];
#pragma unroll
          for (int r = 0; r < 4; ++r)
            C[(size_t)(grow + r) * DM + gcol] = acc[qm][i][qn][j][r] + bo;
        }
    }
#undef STAO
#undef STBO
#undef STAGE_ALLO
#undef READA_O
#undef RB_O
#undef MFMACLO
}

// ---------------------------------------------------------------------------
// Fused conv(K)+fm, conv(V), partial-KV. Register-blocked outer product
// (r1 version — the T14 prefetch variant measured ~+18 µs, reverted).
// Grid (64 bh, 16 chunks of 256 s). Deterministic partials.
// ---------------------------------------------------------------------------
__global__ __launch_bounds__(256) void kv_accum_conv(
    const float* __restrict__ Kg, const float* __restrict__ Vg,
    const float* __restrict__ kc_w, const float* __restrict__ kc_b,
    const float* __restrict__ vc_w, const float* __restrict__ vc_b,
    float* __restrict__ KVp, float* __restrict__ Ksp) {
  const int bh = blockIdx.x;
  const int b = bh >> 4, h = bh & 15;
  const int chunk = blockIdx.y;
  const int s0 = chunk * 256;
  const int t = threadIdx.x;
  const int w = t >> 6, lane = t & 63;
  __shared__ float Kr[34][64], Vr[34][64];
  __shared__ float Kc[32][64], Vc[32][64];
  __shared__ float kw0[64], kw1[64], kw2[64], kb_[64];
  __shared__ float vw0[64], vw1[64], vw2[64], vb_[64];

  if (t < 64) {
    kw0[t] = kc_w[t * 3 + 0]; kw1[t] = kc_w[t * 3 + 1]; kw2[t] = kc_w[t * 3 + 2];
    vw0[t] = vc_w[t * 3 + 0]; vw1[t] = vc_w[t * 3 + 1]; vw2[t] = vc_w[t * 3 + 2];
    kb_[t] = kc_b[t]; vb_[t] = vc_b[t];
  }

  const int d0 = w * 16 + (lane >> 4) * 4;
  const int e0 = (lane & 15) * 4;
  float acc[4][4];
#pragma unroll
  for (int i = 0; i < 4; ++i)
#pragma unroll
    for (int j = 0; j < 4; ++j) acc[i][j] = 0.f;
  float4 ks = make_float4(0.f, 0.f, 0.f, 0.f);
  const size_t gbase = (size_t)b * SS * DM + h * HD;

  for (int c = 0; c < 256; c += 32) {
    __syncthreads();
    for (int idx = t; idx < 544; idx += 256) {
      const int row = idx >> 4, col = (idx & 15) * 4;
      const int s = s0 + c - 2 + row;
      float4 k4 = make_float4(0.f, 0.f, 0.f, 0.f);
      float4 v4 = make_float4(0.f, 0.f, 0.f, 0.f);
      if (s >= 0) {
        k4 = *(const float4*)&Kg[gbase + (size_t)s * DM + col];
        v4 = *(const float4*)&Vg[gbase + (size_t)s * DM + col];
      }
      *(float4*)&Kr[row][col] = k4;
      *(float4*)&Vr[row][col] = v4;
    }
    __syncthreads();
    for (int idx = t; idx < 2048; idx += 256) {
      const int row = idx >> 6, dd = idx & 63;
      float yk = kb_[dd] + kw0[dd] * Kr[row][dd] + kw1[dd] * Kr[row + 1][dd] +
                 kw2[dd] * Kr[row + 2][dd];
      Kc[row][dd] = (yk > 0.f) ? (yk + 1.f) : expf(yk);
      Vc[row][dd] = vb_[dd] + vw0[dd] * Vr[row][dd] + vw1[dd] * Vr[row + 1][dd] +
                    vw2[dd] * Vr[row + 2][dd];
    }
    __syncthreads();
#pragma unroll 2
    for (int ss = 0; ss < 32; ++ss) {
      const float4 k4 = *(const float4*)&Kc[ss][d0];
      const float4 v4 = *(const float4*)&Vc[ss][e0];
      ks.x += k4.x; ks.y += k4.y; ks.z += k4.z; ks.w += k4.w;
      const float kk[4] = {k4.x, k4.y, k4.z, k4.w};
      const float vv[4] = {v4.x, v4.y, v4.z, v4.w};
#pragma unroll
      for (int i = 0; i < 4; ++i)
#pragma unroll
        for (int j = 0; j < 4; ++j) acc[i][j] = fmaf(kk[i], vv[j], acc[i][j]);
    }
  }
  float* kvp = &KVp[((size_t)(bh * 16 + chunk)) * 4096];
#pragma unroll
  for (int i = 0; i < 4; ++i) {
    float4 o = make_float4(acc[i][0], acc[i][1], acc[i][2], acc[i][3]);
    *(float4*)&kvp[(d0 + i) * 64 + e0] = o;
  }
  if ((lane & 15) == 0) {
    float* kp = &Ksp[(bh * 16 + chunk) * 64 + d0];
    kp[0] = ks.x; kp[1] = ks.y; kp[2] = ks.z; kp[3] = ks.w;
  }
}

// Reduce 16 partials; Ksum gets +eps folded in. (unchanged)
__global__ __launch_bounds__(256) void kv_reduce(
    const float* __restrict__ KVp, const float* __restrict__ Ksp,
    float* __restrict__ KV, float* __restrict__ Ksum) {
  const int bh = blockIdx.x;
  const int t = threadIdx.x;
  for (int i = t; i < 4096; i += 256) {
    float s = 0.f;
#pragma unroll
    for (int c = 0; c < 16; ++c) s += KVp[((size_t)(bh * 16 + c)) * 4096 + i];
    KV[(size_t)bh * 4096 + i] = s;
  }
  if (t < 64) {
    float s = 1e-6f;
#pragma unroll
    for (int c = 0; c < 16; ++c) s += Ksp[(bh * 16 + c) * 64 + t];
    Ksum[bh * 64 + t] = s;
  }
}

// ---------------------------------------------------------------------------
// Fused conv(Q)+fm + attention apply. Output written as f16 hi/lo planes
// (exact same numerics as fp32-write + split). Grid (64 bh, 64 chunks).
// ---------------------------------------------------------------------------
__global__ __launch_bounds__(256) void attn_apply_conv(
    const float* __restrict__ Qg, const float* __restrict__ KV,
    const float* __restrict__ Ksum, const float* __restrict__ qc_w,
    const float* __restrict__ qc_b, _Float16* __restrict__ OHi,
    _Float16* __restrict__ OLo) {
  const int bh = blockIdx.x;
  const int b = bh >> 4, h = bh & 15;
  const int s0 = blockIdx.y * 64;
  const int t = threadIdx.x;
  const int w = t >> 6, lane = t & 63;
  __shared__ float Qr[66][64];
  __shared__ float QsT[64][68];
  __shared__ float KVs[64][64];
  __shared__ float pden[64][4];
  __shared__ float kse[64];
  __shared__ float qw0[64], qw1[64], qw2[64], qb_[64];
  const size_t gbase = (size_t)b * SS * DM + h * HD;

  for (int idx = t; idx < 1056; idx += 256) {
    const int row = idx >> 4, col = (idx & 15) * 4;
    const int s = s0 - 2 + row;
    float4 q4 = make_float4(0.f, 0.f, 0.f, 0.f);
    if (s >= 0) q4 = *(const float4*)&Qg[gbase + (size_t)s * DM + col];
    *(float4*)&Qr[row][col] = q4;
  }
  for (int idx = t; idx < 1024; idx += 256) {
    const int row = idx >> 4, col = (idx & 15) * 4;
    *(float4*)&KVs[row][col] = *(const float4*)&KV[(size_t)bh * 4096 + row * 64 + col];
  }
  if (t < 64) {
    kse[t] = Ksum[bh * 64 + t];
    qw0[t] = qc_w[t * 3 + 0]; qw1[t] = qc_w[t * 3 + 1]; qw2[t] = qc_w[t * 3 + 2];
    qb_[t] = qc_b[t];
  }
  __syncthreads();

  {
    const int crow = t >> 2;
    const int db = (t & 3) * 16;
    float denp = 0.f;
#pragma unroll
    for (int q = 0; q < 4; ++q) {
      const float4 xm2 = *(const float4*)&Qr[crow][db + q * 4];
      const float4 xm1 = *(const float4*)&Qr[crow + 1][db + q * 4];
      const float4 xc0 = *(const float4*)&Qr[crow + 2][db + q * 4];
      const float a2[4] = {xm2.x, xm2.y, xm2.z, xm2.w};
      const float a1[4] = {xm1.x, xm1.y, xm1.z, xm1.w};
      const float a0[4] = {xc0.x, xc0.y, xc0.z, xc0.w};
#pragma unroll
      for (int e = 0; e < 4; ++e) {
        const int dd = db + q * 4 + e;
        float y = qb_[dd] + qw0[dd] * a2[e] + qw1[dd] * a1[e] + qw2[dd] * a0[e];
        y = (y > 0.f) ? (y + 1.f) : expf(y);
        denp = fmaf(y, kse[dd], denp);
        QsT[dd][crow] = y;
      }
    }
    pden[crow][t & 3] = denp;
  }
  __syncthreads();

  const int sl0 = w * 16 + (lane >> 4) * 4;
  const int e0 = (lane & 15) * 4;
  float acc[4][4];
#pragma unroll
  for (int i = 0; i < 4; ++i)
#pragma unroll
    for (int j = 0; j < 4; ++j) acc[i][j] = 0.f;
#pragma unroll 2
  for (int d = 0; d < 64; ++d) {
    const float4 q4 = *(const float4*)&QsT[d][sl0];
    const float4 v4 = *(const float4*)&KVs[d][e0];
    const float qq[4] = {q4.x, q4.y, q4.z, q4.w};
    const float vv[4] = {v4.x, v4.y, v4.z, v4.w};
#pragma unroll
    for (int i = 0; i < 4; ++i)
#pragma unroll
      for (int j = 0; j < 4; ++j) acc[i][j] = fmaf(qq[i], vv[j], acc[i][j]);
  }
#pragma unroll
  for (int i = 0; i < 4; ++i) {
    const float4 pd = *(const float4*)&pden[sl0 + i][0];
    const float zz = 1.0f / (pd.x + pd.y + pd.z + pd.w);
    const float o[4] = {acc[i][0] * zz, acc[i][1] * zz, acc[i][2] * zz,
                        acc[i][3] * zz};
    half4v hh, ll;
#pragma unroll
    for (int e = 0; e < 4; ++e) {
      const _Float16 hv = (_Float16)o[e];
      hh[e] = hv;
      ll[e] = (_Float16)(o[e] - (float)hv);
    }
    const size_t base = gbase + (size_t)(s0 + sl0 + i) * DM + e0;
    *(half4v*)&OHi[base] = hh;
    *(half4v*)&OLo[base] = ll;
  }
}

// ---------------------------------------------------------------------------
extern "C" void kernel_launch(void* const* d_in, const int* in_sizes, int n_in,
                              void* d_out, int out_size, void* d_ws, size_t ws_size,
                              hipStream_t stream) {
  const float* query = (const float*)d_in[0];
  const float* key   = (const float*)d_in[1];
  const float* value = (const float*)d_in[2];
  const float* q_w = (const float*)d_in[3];
  const float* q_b = (const float*)d_in[4];
  const float* k_w = (const float*)d_in[5];
  const float* k_b = (const float*)d_in[6];
  const float* v_w = (const float*)d_in[7];
  const float* v_b = (const float*)d_in[8];
  const float* o_w = (const float*)d_in[9];
  const float* o_b = (const float*)d_in[10];
  const float* qc_w = (const float*)d_in[11];
  const float* qc_b = (const float*)d_in[12];
  const float* kc_w = (const float*)d_in[13];
  const float* kc_b = (const float*)d_in[14];
  const float* vc_w = (const float*)d_in[15];
  const float* vc_b = (const float*)d_in[16];
  float* out = (float*)d_out;

  // Workspace (~226 MB)
  float* ws = (float*)d_ws;
  float* buf0 = ws;                    // raw K proj -> attn f16 hi/lo out
  float* buf1 = ws + TSZ;              // raw V proj
  float* buf2 = ws + 2 * TSZ;          // raw Q proj
  _Float16* Whi = (_Float16*)(ws + 3 * TSZ);  // 4 x 2 MB (k,v,q,o)
  _Float16* Wlo = Whi + 4 * (1 << 20);
  float* KVp  = (float*)(Wlo + 4 * (1 << 20));   // 64*16*4096
  float* Ksp  = KVp + (size_t)64 * 16 * 4096;    // 64*16*64
  float* KV   = Ksp + 64 * 16 * 64;
  float* Ksum = KV + (size_t)64 * 4096;

  _Float16* WhiO = Whi + 3 * (1 << 20);
  _Float16* WloO = Wlo + 3 * (1 << 20);
  // attn output hi/lo planes overlay buf0 (K-proj dead by then): 32+32 MB
  _Float16* OHi = (_Float16*)buf0;
  _Float16* OLo = OHi + TSZ;

  const int nW4 = DM * DM / 4;

  split_w4<<<dim3(nW4 / 256, 4), 256, 0, stream>>>(k_w, v_w, q_w, o_w, Whi, Wlo);

  qkv_gemm9<<<dim3(4, 64, 3), 512, 0, stream>>>(
      key, value, query, Whi, Wlo, k_b, v_b, q_b, buf0, buf1, buf2);

  kv_accum_conv<<<dim3(64, 16), 256, 0, stream>>>(buf0, buf1, kc_w, kc_b, vc_w,
                                                  vc_b, KVp, Ksp);
  kv_reduce<<<64, 256, 0, stream>>>(KVp, Ksp, KV, Ksum);

  attn_apply_conv<<<dim3(64, 64), 256, 0, stream>>>(buf2, KV, Ksum, qc_w, qc_b,
                                                    OHi, OLo);

  o_gemm9<<<dim3(4, 64), 512, 0, stream>>>(OHi, OLo, WhiO, WloO, o_b, out);
}

// Round 5
// 612.626 us; speedup vs baseline: 1.2858x; 1.2858x over previous
//
#include <hip/hip_runtime.h>
#include <hip/hip_bf16.h>
#include <math.h>

// Problem constants
#define BB 4
#define SS 4096
#define DM 1024
#define HH 16
#define HD 64
#define NTOK (BB * SS)          // 16384 rows
#define TSZ ((size_t)NTOK * DM) // 16777216 elements per activation plane

typedef _Float16 half8 __attribute__((ext_vector_type(8)));
typedef _Float16 half4v __attribute__((ext_vector_type(4)));
typedef float floatx4 __attribute__((ext_vector_type(4)));

__device__ __forceinline__ void gload16(const void* g, void* l) {
  __builtin_amdgcn_global_load_lds(
      (const __attribute__((address_space(1))) void*)g,
      (__attribute__((address_space(3))) void*)l, 16, 0, 0);
}

#define WAIT4 asm volatile("s_waitcnt vmcnt(4)" ::: "memory")
#define WAIT2 asm volatile("s_waitcnt vmcnt(2)" ::: "memory")
#define WAIT0 asm volatile("s_waitcnt vmcnt(0)" ::: "memory")
#define BARR __builtin_amdgcn_s_barrier()

// 2-term f32-emulation: A single f16 plane, B hi/lo planes.
// err ~ 2^-12-relative on A (ref carries tf32-class error; see journal).
#define MM2(A_, ah_, bh_, bl_)                                        \
  A_ = __builtin_amdgcn_mfma_f32_16x16x32_f16(ah_, bh_, A_, 0, 0, 0); \
  A_ = __builtin_amdgcn_mfma_f32_16x16x32_f16(ah_, bl_, A_, 0, 0, 0)

__device__ __forceinline__ void cvh(const float4 u0, const float4 u1,
                                    half8& h) {
  h[0] = (_Float16)u0.x; h[1] = (_Float16)u0.y;
  h[2] = (_Float16)u0.z; h[3] = (_Float16)u0.w;
  h[4] = (_Float16)u1.x; h[5] = (_Float16)u1.y;
  h[6] = (_Float16)u1.z; h[7] = (_Float16)u1.w;
}

// ---------------------------------------------------------------------------
// All 4 weight matrices split into (hi,lo) f16 planes in one dispatch.
// Arena: hi/lo each 4*(1<<20) f16. Order: 0=k_w 1=v_w 2=q_w 3=o_w.
// ---------------------------------------------------------------------------
__global__ __launch_bounds__(256) void split_w4(
    const float* __restrict__ w0, const float* __restrict__ w1,
    const float* __restrict__ w2, const float* __restrict__ w3,
    _Float16* __restrict__ hi, _Float16* __restrict__ lo) {
  const int wi = blockIdx.y;
  const float* src = (wi == 0) ? w0 : (wi == 1) ? w1 : (wi == 2) ? w2 : w3;
  const int i = blockIdx.x * 256 + threadIdx.x;          // < 262144
  const size_t off = ((size_t)wi << 20) >> 2;            // in float4 units
  const float4 x = ((const float4*)src)[i];
  half4v h, l;
  h.x = (_Float16)x.x; l.x = (_Float16)(x.x - (float)h.x);
  h.y = (_Float16)x.y; l.y = (_Float16)(x.y - (float)h.y);
  h.z = (_Float16)x.z; l.z = (_Float16)(x.z - (float)h.z);
  h.w = (_Float16)x.w; l.w = (_Float16)(x.w - (float)h.w);
  ((half4v*)hi)[off + i] = h;
  ((half4v*)lo)[off + i] = l;
}

// ---------------------------------------------------------------------------
// 256x256-tile 4-phase QKV GEMM (16x16x32 f16 MFMA, r1/r3-proven schedule).
// 2-term emulation: A single f16 plane (converted at fragment read), B hi/lo.
// B fragments held in regs across QM0->QM1 phases. Raw fp32 A staged direct
// via global_load_lds. XOR-swizzled LDS, counted vmcnt(4), setprio,
// bijective XCD swizzle.
// ---------------------------------------------------------------------------
__global__ __launch_bounds__(512, 2) void qkv_gemm10(
    const float* __restrict__ Ak, const float* __restrict__ Av,
    const float* __restrict__ Aq, const _Float16* __restrict__ WhiA,
    const _Float16* __restrict__ WloA, const float* __restrict__ bk,
    const float* __restrict__ bv, const float* __restrict__ bq,
    float* __restrict__ Ck, float* __restrict__ Cv, float* __restrict__ Cq) {
  __shared__ float sA[2][256 * 32];      // raw fp32 A tile, 32 KB per buf
  __shared__ _Float16 sB[2][256 * 64];   // f16 hi|lo pair rows, 32 KB per buf

  const int z = blockIdx.z;
  const float* A = (z == 0) ? Ak : (z == 1) ? Av : Aq;
  const float* bias = (z == 0) ? bk : (z == 1) ? bv : bq;
  float* C = (z == 0) ? Ck : (z == 1) ? Cv : Cq;
  const _Float16* Whi = WhiA + ((size_t)z << 20);
  const _Float16* Wlo = WloA + ((size_t)z << 20);

  const int t = threadIdx.x;
  const int wav = t >> 6, lane = t & 63;
  const int wr = wav >> 2, wc = wav & 3;  // 2 x 4 wave grid

  // bijective XCD swizzle: each XCD owns one (N-half, M-sixteenth) chunk
  const int wg = blockIdx.y * 4 + blockIdx.x;  // 0..255
  const int xcd = wg & 7, cidx = wg >> 3;      // cidx 0..31
  const int bm = ((xcd >> 1) * 16 + (cidx >> 1)) * 256;
  const int bn = ((xcd & 1) * 2 + (cidx & 1)) * 256;

  // --- staging source prep (source pre-swizzled so linear LDS = swizzled) ---
  const int lrow = wav * 8 + (lane >> 3);       // row within a 64-row issue
  const int cpr = (lane & 7) ^ (lane >> 3);     // global slot for dest slot l&7
  const float* pA0 = A + (size_t)(bm + lrow) * DM + cpr * 4;
  const _Float16* pB0 =
      ((cpr < 4) ? Whi : Wlo) + (size_t)(bn + lrow) * DM + (cpr & 3) * 8;
  const int ldsArow = wav * 8 * 32;  // float units (wave-uniform)
  const int ldsBrow = wav * 8 * 64;  // f16 units  (wave-uniform)

#define STA(buf, rb, k0) \
  gload16(pA0 + (size_t)(rb) * DM + (k0), &sA[buf][(rb) * 32 + ldsArow])
#define STB(buf, rb, k0) \
  gload16(pB0 + (size_t)(rb) * DM + (k0), &sB[buf][(rb) * 64 + ldsBrow])

  // prologue: stage tile 0, issue order = A0 A0 B0 B0 B1 B1 A1 A1
  STA(0, 0, 0); STA(0, 64, 0);
  STB(0, 0, 0); STB(0, 64, 0);
  STB(0, 128, 0); STB(0, 192, 0);
  STA(0, 128, 0); STA(0, 192, 0);

  // --- ds_read fragment offsets (swizzled: slot ^= row&7, row&7 == fm&7) ---
  const int fm = lane & 15;
  const int sw = fm & 7;
  const int kq = lane >> 4;
  int baseA[4], baseB[2];
#pragma unroll
  for (int i = 0; i < 4; ++i) baseA[i] = (wr * 64 + i * 16 + fm) * 32;
#pragma unroll
  for (int j = 0; j < 2; ++j) baseB[j] = (wc * 32 + j * 16 + fm) * 64;
  const int aS0 = ((kq * 2) ^ sw) * 4;       // fp32 slots (16B each)
  const int aS1 = ((kq * 2 + 1) ^ sw) * 4;
  const int bSh = (kq ^ sw) * 8;             // f16 hi slot
  const int bSl = ((kq + 4) ^ sw) * 8;       // f16 lo slot

  floatx4 acc[2][4][2][2];
#pragma unroll
  for (int i = 0; i < 2; ++i)
#pragma unroll
    for (int j = 0; j < 4; ++j)
#pragma unroll
      for (int k = 0; k < 2; ++k)
#pragma unroll
        for (int l = 0; l < 2; ++l)
          acc[i][j][k][l] = (floatx4){0.f, 0.f, 0.f, 0.f};

  half8 ah[4];
  half8 b0h0, b0l0, b0h1, b0l1;   // B fragments, QN=0 (live phases 1->3)
  half8 b1h0, b1l0, b1h1, b1l1;   // B fragments, QN=1 (live phases 2->4)

#define READA_Q(cur_, QM)                                       \
  _Pragma("unroll") for (int i_ = 0; i_ < 4; ++i_) {            \
    const float4 u0_ =                                          \
        *(const float4*)&sA[cur_][baseA[i_] + (QM) * 4096 + aS0]; \
    const float4 u1_ =                                          \
        *(const float4*)&sA[cur_][baseA[i_] + (QM) * 4096 + aS1]; \
    cvh(u0_, u1_, ah[i_]);                                      \
  }

#define RB_Q(cur_, QN, H0, L0, H1, L1)                          \
  H0 = *(const half8*)&sB[cur_][baseB[0] + (QN) * 8192 + bSh];  \
  L0 = *(const half8*)&sB[cur_][baseB[0] + (QN) * 8192 + bSl];  \
  H1 = *(const half8*)&sB[cur_][baseB[1] + (QN) * 8192 + bSh];  \
  L1 = *(const half8*)&sB[cur_][baseB[1] + (QN) * 8192 + bSl]

#define MFMACL(QM, QN, H0, L0, H1, L1)                          \
  __builtin_amdgcn_s_setprio(1);                                \
  _Pragma("unroll") for (int i_ = 0; i_ < 4; ++i_) {            \
    MM2(acc[QM][i_][QN][0], ah[i_], H0, L0);                    \
    MM2(acc[QM][i_][QN][1], ah[i_], H1, L1);                    \
  }                                                             \
  __builtin_amdgcn_s_setprio(0)

  // main loop: tiles 0..30 with prefetch of tile tt+1
  for (int tt = 0; tt < 31; ++tt) {
    const int cur = tt & 1, nxt = cur ^ 1;
    const int k1 = tt * 32 + 32;
    WAIT4; BARR;                         // drains A0,B0 of tile tt
    READA_Q(cur, 0);
    RB_Q(cur, 0, b0h0, b0l0, b0h1, b0l1);
    STA(nxt, 0, k1); STA(nxt, 64, k1);
    MFMACL(0, 0, b0h0, b0l0, b0h1, b0l1);
    BARR;
    WAIT4; BARR;                         // drains B1 (QN=1 rows)
    RB_Q(cur, 1, b1h0, b1l0, b1h1, b1l1);
    STB(nxt, 0, k1); STB(nxt, 64, k1);
    MFMACL(0, 1, b1h0, b1l0, b1h1, b1l1);
    BARR;
    WAIT4; BARR;                         // drains A1
    READA_Q(cur, 1);
    STB(nxt, 128, k1); STB(nxt, 192, k1);
    MFMACL(1, 0, b0h0, b0l0, b0h1, b0l1);   // B regs reused, no ds_read
    BARR;
    STA(nxt, 128, k1); STA(nxt, 192, k1);
    MFMACL(1, 1, b1h0, b1l0, b1h1, b1l1);   // B regs reused, no ds_read
  }
  // epilogue tile 31 (cur = 1), no prefetch: drain 4 -> 2 -> 0
  WAIT4; BARR;
  READA_Q(1, 0);
  RB_Q(1, 0, b0h0, b0l0, b0h1, b0l1);
  MFMACL(0, 0, b0h0, b0l0, b0h1, b0l1);
  BARR;
  WAIT2; BARR;
  RB_Q(1, 1, b1h0, b1l0, b1h1, b1l1);
  MFMACL(0, 1, b1h0, b1l0, b1h1, b1l1);
  BARR;
  WAIT0; BARR;
  READA_Q(1, 1);
  MFMACL(1, 0, b0h0, b0l0, b0h1, b0l1);
  MFMACL(1, 1, b1h0, b1l0, b1h1, b1l1);

  const int cr = (lane >> 4) * 4;
#pragma unroll
  for (int qm = 0; qm < 2; ++qm)
#pragma unroll
    for (int i = 0; i < 4; ++i) {
      const int grow = bm + qm * 128 + wr * 64 + i * 16 + cr;
#pragma unroll
      for (int qn = 0; qn < 2; ++qn)
#pragma unroll
        for (int j = 0; j < 2; ++j) {
          const int gcol = bn + qn * 128 + wc * 32 + j * 16 + fm;
          const float bo = bias[gcol];
#pragma unroll
          for (int r = 0; r < 4; ++r)
            C[(size_t)(grow + r) * DM + gcol] = acc[qm][i][qn][j][r] + bo;
        }
    }
#undef STA
#undef STB
#undef READA_Q
#undef RB_Q
#undef MFMACL
}

// ---------------------------------------------------------------------------
// Output-projection GEMM: 2-term (A hi plane only x B hi/lo). A staged as
// hi/lo pair rows (layout unchanged; lo rows staged but unread). Same
// r3 schedule with B-reg reuse + dual barrier.
// ---------------------------------------------------------------------------
__global__ __launch_bounds__(512, 2) void o_gemm10(
    const _Float16* __restrict__ Ahi, const _Float16* __restrict__ Alo,
    const _Float16* __restrict__ Whi, const _Float16* __restrict__ Wlo,
    const float* __restrict__ bias, float* __restrict__ C) {
  __shared__ _Float16 sA[2][256 * 64];
  __shared__ _Float16 sB[2][256 * 64];

  const int t = threadIdx.x;
  const int wav = t >> 6, lane = t & 63;
  const int wr = wav >> 2, wc = wav & 3;

  const int wg = blockIdx.y * 4 + blockIdx.x;
  const int xcd = wg & 7, cidx = wg >> 3;
  const int bm = ((xcd >> 1) * 16 + (cidx >> 1)) * 256;
  const int bn = ((xcd & 1) * 2 + (cidx & 1)) * 256;

  const int lrow = wav * 8 + (lane >> 3);
  const int cpr = (lane & 7) ^ (lane >> 3);
  const _Float16* pA0 =
      ((cpr < 4) ? Ahi : Alo) + (size_t)(bm + lrow) * DM + (cpr & 3) * 8;
  const _Float16* pB0 =
      ((cpr < 4) ? Whi : Wlo) + (size_t)(bn + lrow) * DM + (cpr & 3) * 8;
  const int ldsRow = wav * 8 * 64;

#define STAO(buf, rb, k0) \
  gload16(pA0 + (size_t)(rb) * DM + (k0), &sA[buf][(rb) * 64 + ldsRow])
#define STBO(buf, rb, k0) \
  gload16(pB0 + (size_t)(rb) * DM + (k0), &sB[buf][(rb) * 64 + ldsRow])

  STAO(0, 0, 0); STAO(0, 64, 0);
  STBO(0, 0, 0); STBO(0, 64, 0);
  STBO(0, 128, 0); STBO(0, 192, 0);
  STAO(0, 128, 0); STAO(0, 192, 0);

  const int fm = lane & 15;
  const int sw = fm & 7;
  const int kq = lane >> 4;
  int baseA[4], baseB[2];
#pragma unroll
  for (int i = 0; i < 4; ++i) baseA[i] = (wr * 64 + i * 16 + fm) * 64;
#pragma unroll
  for (int j = 0; j < 2; ++j) baseB[j] = (wc * 32 + j * 16 + fm) * 64;
  const int bSh = (kq ^ sw) * 8;
  const int bSl = ((kq + 4) ^ sw) * 8;

  floatx4 acc[2][4][2][2];
#pragma unroll
  for (int i = 0; i < 2; ++i)
#pragma unroll
    for (int j = 0; j < 4; ++j)
#pragma unroll
      for (int k = 0; k < 2; ++k)
#pragma unroll
        for (int l = 0; l < 2; ++l)
          acc[i][j][k][l] = (floatx4){0.f, 0.f, 0.f, 0.f};

  half8 ah[4];
  half8 b0h0, b0l0, b0h1, b0l1;
  half8 b1h0, b1l0, b1h1, b1l1;

#define READA_O(cur_, QM)                                                 \
  _Pragma("unroll") for (int i_ = 0; i_ < 4; ++i_) {                      \
    ah[i_] = *(const half8*)&sA[cur_][baseA[i_] + (QM) * 8192 + bSh];     \
  }

#define RB_O(cur_, QN, H0, L0, H1, L1)                          \
  H0 = *(const half8*)&sB[cur_][baseB[0] + (QN) * 8192 + bSh];  \
  L0 = *(const half8*)&sB[cur_][baseB[0] + (QN) * 8192 + bSl];  \
  H1 = *(const half8*)&sB[cur_][baseB[1] + (QN) * 8192 + bSh];  \
  L1 = *(const half8*)&sB[cur_][baseB[1] + (QN) * 8192 + bSl]

#define MFMACLO(QM, QN, H0, L0, H1, L1)                         \
  __builtin_amdgcn_s_setprio(1);                                \
  _Pragma("unroll") for (int i_ = 0; i_ < 4; ++i_) {            \
    MM2(acc[QM][i_][QN][0], ah[i_], H0, L0);                    \
    MM2(acc[QM][i_][QN][1], ah[i_], H1, L1);                    \
  }                                                             \
  __builtin_amdgcn_s_setprio(0)

  for (int tt = 0; tt < 31; ++tt) {
    const int cur = tt & 1, nxt = cur ^ 1;
    const int k1 = tt * 32 + 32;
    WAIT4; BARR;
    READA_O(cur, 0);
    RB_O(cur, 0, b0h0, b0l0, b0h1, b0l1);
    STAO(nxt, 0, k1); STAO(nxt, 64, k1);
    MFMACLO(0, 0, b0h0, b0l0, b0h1, b0l1);
    BARR;
    WAIT4; BARR;
    RB_O(cur, 1, b1h0, b1l0, b1h1, b1l1);
    STBO(nxt, 0, k1); STBO(nxt, 64, k1);
    MFMACLO(0, 1, b1h0, b1l0, b1h1, b1l1);
    BARR;
    WAIT4; BARR;
    READA_O(cur, 1);
    STBO(nxt, 128, k1); STBO(nxt, 192, k1);
    MFMACLO(1, 0, b0h0, b0l0, b0h1, b0l1);
    BARR;
    STAO(nxt, 128, k1); STAO(nxt, 192, k1);
    MFMACLO(1, 1, b1h0, b1l0, b1h1, b1l1);
  }
  WAIT4; BARR;
  READA_O(1, 0);
  RB_O(1, 0, b0h0, b0l0, b0h1, b0l1);
  MFMACLO(0, 0, b0h0, b0l0, b0h1, b0l1);
  BARR;
  WAIT2; BARR;
  RB_O(1, 1, b1h0, b1l0, b1h1, b1l1);
  MFMACLO(0, 1, b1h0, b1l0, b1h1, b1l1);
  BARR;
  WAIT0; BARR;
  READA_O(1, 1);
  MFMACLO(1, 0, b0h0, b0l0, b0h1, b0l1);
  MFMACLO(1, 1, b1h0, b1l0, b1h1, b1l1);

  const int cr = (lane >> 4) * 4;
#pragma unroll
  for (int qm = 0; qm < 2; ++qm)
#pragma unroll
    for (int i = 0; i < 4; ++i) {
      const int grow = bm + qm * 128 + wr * 64 + i * 16 + cr;
#pragma unroll
      for (int qn = 0; qn < 2; ++qn)
#pragma unroll
        for (int j = 0; j < 2; ++j) {
          const int gcol = bn + qn * 128 + wc * 32 + j * 16 + fm;
          const float bo = bias[gcol];
#pragma unroll
          for (int r = 0; r < 4; ++r)
            C[(size_t)(grow + r) * DM + gcol] = acc[qm][i][qn][j][r] + bo;
        }
    }
#undef STAO
#undef STBO
#undef READA_O
#undef RB_O
#undef MFMACLO
}

// ---------------------------------------------------------------------------
// Fused conv(K)+fm, conv(V), partial-KV. Register-blocked outer product
// (r1 version — T14 prefetch variant measured +18 µs, reverted).
// Grid (64 bh, 16 chunks of 256 s). Deterministic partials.
// ---------------------------------------------------------------------------
__global__ __launch_bounds__(256) void kv_accum_conv(
    const float* __restrict__ Kg, const float* __restrict__ Vg,
    const float* __restrict__ kc_w, const float* __restrict__ kc_b,
    const float* __restrict__ vc_w, const float* __restrict__ vc_b,
    float* __restrict__ KVp, float* __restrict__ Ksp) {
  const int bh = blockIdx.x;
  const int b = bh >> 4, h = bh & 15;
  const int chunk = blockIdx.y;
  const int s0 = chunk * 256;
  const int t = threadIdx.x;
  const int w = t >> 6, lane = t & 63;
  __shared__ float Kr[34][64], Vr[34][64];
  __shared__ float Kc[32][64], Vc[32][64];
  __shared__ float kw0[64], kw1[64], kw2[64], kb_[64];
  __shared__ float vw0[64], vw1[64], vw2[64], vb_[64];

  if (t < 64) {
    kw0[t] = kc_w[t * 3 + 0]; kw1[t] = kc_w[t * 3 + 1]; kw2[t] = kc_w[t * 3 + 2];
    vw0[t] = vc_w[t * 3 + 0]; vw1[t] = vc_w[t * 3 + 1]; vw2[t] = vc_w[t * 3 + 2];
    kb_[t] = kc_b[t]; vb_[t] = vc_b[t];
  }

  const int d0 = w * 16 + (lane >> 4) * 4;
  const int e0 = (lane & 15) * 4;
  float acc[4][4];
#pragma unroll
  for (int i = 0; i < 4; ++i)
#pragma unroll
    for (int j = 0; j < 4; ++j) acc[i][j] = 0.f;
  float4 ks = make_float4(0.f, 0.f, 0.f, 0.f);
  const size_t gbase = (size_t)b * SS * DM + h * HD;

  for (int c = 0; c < 256; c += 32) {
    __syncthreads();
    for (int idx = t; idx < 544; idx += 256) {
      const int row = idx >> 4, col = (idx & 15) * 4;
      const int s = s0 + c - 2 + row;
      float4 k4 = make_float4(0.f, 0.f, 0.f, 0.f);
      float4 v4 = make_float4(0.f, 0.f, 0.f, 0.f);
      if (s >= 0) {
        k4 = *(const float4*)&Kg[gbase + (size_t)s * DM + col];
        v4 = *(const float4*)&Vg[gbase + (size_t)s * DM + col];
      }
      *(float4*)&Kr[row][col] = k4;
      *(float4*)&Vr[row][col] = v4;
    }
    __syncthreads();
    for (int idx = t; idx < 2048; idx += 256) {
      const int row = idx >> 6, dd = idx & 63;
      float yk = kb_[dd] + kw0[dd] * Kr[row][dd] + kw1[dd] * Kr[row + 1][dd] +
                 kw2[dd] * Kr[row + 2][dd];
      Kc[row][dd] = (yk > 0.f) ? (yk + 1.f) : expf(yk);
      Vc[row][dd] = vb_[dd] + vw0[dd] * Vr[row][dd] + vw1[dd] * Vr[row + 1][dd] +
                    vw2[dd] * Vr[row + 2][dd];
    }
    __syncthreads();
#pragma unroll 2
    for (int ss = 0; ss < 32; ++ss) {
      const float4 k4 = *(const float4*)&Kc[ss][d0];
      const float4 v4 = *(const float4*)&Vc[ss][e0];
      ks.x += k4.x; ks.y += k4.y; ks.z += k4.z; ks.w += k4.w;
      const float kk[4] = {k4.x, k4.y, k4.z, k4.w};
      const float vv[4] = {v4.x, v4.y, v4.z, v4.w};
#pragma unroll
      for (int i = 0; i < 4; ++i)
#pragma unroll
        for (int j = 0; j < 4; ++j) acc[i][j] = fmaf(kk[i], vv[j], acc[i][j]);
    }
  }
  float* kvp = &KVp[((size_t)(bh * 16 + chunk)) * 4096];
#pragma unroll
  for (int i = 0; i < 4; ++i) {
    float4 o = make_float4(acc[i][0], acc[i][1], acc[i][2], acc[i][3]);
    *(float4*)&kvp[(d0 + i) * 64 + e0] = o;
  }
  if ((lane & 15) == 0) {
    float* kp = &Ksp[(bh * 16 + chunk) * 64 + d0];
    kp[0] = ks.x; kp[1] = ks.y; kp[2] = ks.z; kp[3] = ks.w;
  }
}

// Reduce 16 partials; Ksum gets +eps folded in. (unchanged)
__global__ __launch_bounds__(256) void kv_reduce(
    const float* __restrict__ KVp, const float* __restrict__ Ksp,
    float* __restrict__ KV, float* __restrict__ Ksum) {
  const int bh = blockIdx.x;
  const int t = threadIdx.x;
  for (int i = t; i < 4096; i += 256) {
    float s = 0.f;
#pragma unroll
    for (int c = 0; c < 16; ++c) s += KVp[((size_t)(bh * 16 + c)) * 4096 + i];
    KV[(size_t)bh * 4096 + i] = s;
  }
  if (t < 64) {
    float s = 1e-6f;
#pragma unroll
    for (int c = 0; c < 16; ++c) s += Ksp[(bh * 16 + c) * 64 + t];
    Ksum[bh * 64 + t] = s;
  }
}

// ---------------------------------------------------------------------------
// Fused conv(Q)+fm + attention apply. Output written as f16 hi/lo planes.
// Grid (64 bh, 64 chunks). (unchanged)
// ---------------------------------------------------------------------------
__global__ __launch_bounds__(256) void attn_apply_conv(
    const float* __restrict__ Qg, const float* __restrict__ KV,
    const float* __restrict__ Ksum, const float* __restrict__ qc_w,
    const float* __restrict__ qc_b, _Float16* __restrict__ OHi,
    _Float16* __restrict__ OLo) {
  const int bh = blockIdx.x;
  const int b = bh >> 4, h = bh & 15;
  const int s0 = blockIdx.y * 64;
  const int t = threadIdx.x;
  const int w = t >> 6, lane = t & 63;
  __shared__ float Qr[66][64];
  __shared__ float QsT[64][68];
  __shared__ float KVs[64][64];
  __shared__ float pden[64][4];
  __shared__ float kse[64];
  __shared__ float qw0[64], qw1[64], qw2[64], qb_[64];
  const size_t gbase = (size_t)b * SS * DM + h * HD;

  for (int idx = t; idx < 1056; idx += 256) {
    const int row = idx >> 4, col = (idx & 15) * 4;
    const int s = s0 - 2 + row;
    float4 q4 = make_float4(0.f, 0.f, 0.f, 0.f);
    if (s >= 0) q4 = *(const float4*)&Qg[gbase + (size_t)s * DM + col];
    *(float4*)&Qr[row][col] = q4;
  }
  for (int idx = t; idx < 1024; idx += 256) {
    const int row = idx >> 4, col = (idx & 15) * 4;
    *(float4*)&KVs[row][col] = *(const float4*)&KV[(size_t)bh * 4096 + row * 64 + col];
  }
  if (t < 64) {
    kse[t] = Ksum[bh * 64 + t];
    qw0[t] = qc_w[t * 3 + 0]; qw1[t] = qc_w[t * 3 + 1]; qw2[t] = qc_w[t * 3 + 2];
    qb_[t] = qc_b[t];
  }
  __syncthreads();

  {
    const int crow = t >> 2;
    const int db = (t & 3) * 16;
    float denp = 0.f;
#pragma unroll
    for (int q = 0; q < 4; ++q) {
      const float4 xm2 = *(const float4*)&Qr[crow][db + q * 4];
      const float4 xm1 = *(const float4*)&Qr[crow + 1][db + q * 4];
      const float4 xc0 = *(const float4*)&Qr[crow + 2][db + q * 4];
      const float a2[4] = {xm2.x, xm2.y, xm2.z, xm2.w};
      const float a1[4] = {xm1.x, xm1.y, xm1.z, xm1.w};
      const float a0[4] = {xc0.x, xc0.y, xc0.z, xc0.w};
#pragma unroll
      for (int e = 0; e < 4; ++e) {
        const int dd = db + q * 4 + e;
        float y = qb_[dd] + qw0[dd] * a2[e] + qw1[dd] * a1[e] + qw2[dd] * a0[e];
        y = (y > 0.f) ? (y + 1.f) : expf(y);
        denp = fmaf(y, kse[dd], denp);
        QsT[dd][crow] = y;
      }
    }
    pden[crow][t & 3] = denp;
  }
  __syncthreads();

  const int sl0 = w * 16 + (lane >> 4) * 4;
  const int e0 = (lane & 15) * 4;
  float acc[4][4];
#pragma unroll
  for (int i = 0; i < 4; ++i)
#pragma unroll
    for (int j = 0; j < 4; ++j) acc[i][j] = 0.f;
#pragma unroll 2
  for (int d = 0; d < 64; ++d) {
    const float4 q4 = *(const float4*)&QsT[d][sl0];
    const float4 v4 = *(const float4*)&KVs[d][e0];
    const float qq[4] = {q4.x, q4.y, q4.z, q4.w};
    const float vv[4] = {v4.x, v4.y, v4.z, v4.w};
#pragma unroll
    for (int i = 0; i < 4; ++i)
#pragma unroll
      for (int j = 0; j < 4; ++j) acc[i][j] = fmaf(qq[i], vv[j], acc[i][j]);
  }
#pragma unroll
  for (int i = 0; i < 4; ++i) {
    const float4 pd = *(const float4*)&pden[sl0 + i][0];
    const float zz = 1.0f / (pd.x + pd.y + pd.z + pd.w);
    const float o[4] = {acc[i][0] * zz, acc[i][1] * zz, acc[i][2] * zz,
                        acc[i][3] * zz};
    half4v hh, ll;
#pragma unroll
    for (int e = 0; e < 4; ++e) {
      const _Float16 hv = (_Float16)o[e];
      hh[e] = hv;
      ll[e] = (_Float16)(o[e] - (float)hv);
    }
    const size_t base = gbase + (size_t)(s0 + sl0 + i) * DM + e0;
    *(half4v*)&OHi[base] = hh;
    *(half4v*)&OLo[base] = ll;
  }
}

// ---------------------------------------------------------------------------
extern "C" void kernel_launch(void* const* d_in, const int* in_sizes, int n_in,
                              void* d_out, int out_size, void* d_ws, size_t ws_size,
                              hipStream_t stream) {
  const float* query = (const float*)d_in[0];
  const float* key   = (const float*)d_in[1];
  const float* value = (const float*)d_in[2];
  const float* q_w = (const float*)d_in[3];
  const float* q_b = (const float*)d_in[4];
  const float* k_w = (const float*)d_in[5];
  const float* k_b = (const float*)d_in[6];
  const float* v_w = (const float*)d_in[7];
  const float* v_b = (const float*)d_in[8];
  const float* o_w = (const float*)d_in[9];
  const float* o_b = (const float*)d_in[10];
  const float* qc_w = (const float*)d_in[11];
  const float* qc_b = (const float*)d_in[12];
  const float* kc_w = (const float*)d_in[13];
  const float* kc_b = (const float*)d_in[14];
  const float* vc_w = (const float*)d_in[15];
  const float* vc_b = (const float*)d_in[16];
  float* out = (float*)d_out;

  // Workspace (~226 MB)
  float* ws = (float*)d_ws;
  float* buf0 = ws;                    // raw K proj -> attn f16 hi/lo out
  float* buf1 = ws + TSZ;              // raw V proj
  float* buf2 = ws + 2 * TSZ;          // raw Q proj
  _Float16* Whi = (_Float16*)(ws + 3 * TSZ);  // 4 x 2 MB (k,v,q,o)
  _Float16* Wlo = Whi + 4 * (1 << 20);
  float* KVp  = (float*)(Wlo + 4 * (1 << 20));   // 64*16*4096
  float* Ksp  = KVp + (size_t)64 * 16 * 4096;    // 64*16*64
  float* KV   = Ksp + 64 * 16 * 64;
  float* Ksum = KV + (size_t)64 * 4096;

  _Float16* WhiO = Whi + 3 * (1 << 20);
  _Float16* WloO = Wlo + 3 * (1 << 20);
  // attn output hi/lo planes overlay buf0 (K-proj dead by then): 32+32 MB
  _Float16* OHi = (_Float16*)buf0;
  _Float16* OLo = OHi + TSZ;

  const int nW4 = DM * DM / 4;

  split_w4<<<dim3(nW4 / 256, 4), 256, 0, stream>>>(k_w, v_w, q_w, o_w, Whi, Wlo);

  qkv_gemm10<<<dim3(4, 64, 3), 512, 0, stream>>>(
      key, value, query, Whi, Wlo, k_b, v_b, q_b, buf0, buf1, buf2);

  kv_accum_conv<<<dim3(64, 16), 256, 0, stream>>>(buf0, buf1, kc_w, kc_b, vc_w,
                                                  vc_b, KVp, Ksp);
  kv_reduce<<<64, 256, 0, stream>>>(KVp, Ksp, KV, Ksum);

  attn_apply_conv<<<dim3(64, 64), 256, 0, stream>>>(buf2, KV, Ksum, qc_w, qc_b,
                                                    OHi, OLo);

  o_gemm10<<<dim3(4, 64), 512, 0, stream>>>(OHi, OLo, WhiO, WloO, o_b, out);
}